// Round 1
// baseline (86.070 us; speedup 1.0000x reference)
//
#include <hip/hip_runtime.h>
#include <math.h>

// Problem constants
#define BATCH 4
#define NPTS  2048
#define NT    256
#define TM    128                  // tile rows per block
#define TN    128                  // tile cols per block
#define CH    (NPTS / TN)          // 16 chunks per dimension
#define ROWS_TOT (BATCH * NPTS)    // 8192
#define RB_BLOCKS (ROWS_TOT / 128) // 64 rowreduce blocks
#define CHUNK_F (CH * ROWS_TOT)    // 131072 floats per partial array

// Workspace layout (float units). All partial regions written unconditionally
// before being read -> no init needed despite 0xAA poison. The completion
// counter IS explicitly zeroed by the pairwise grid each launch (runs before
// rowreduce in stream order), so graph replay / re-poison is safe.
// Dedup insight: the 5 former "problems" are only 3 distinct matrices:
//   A = pairwise(t1h, t1): rowmin -> dist1, colmin -> dist2
//   B = pairwise(y0, t0):  rowmin+argmin (clamped keys), colmin -> c1
//   C = pairwise(y0, t1):  rowmin only
#define OFF_AROW 0                     // [16][8192] f : A row partial mins (unclamped)
#define OFF_ACOL (1 * CHUNK_F)         // [16][8192] f : A col partial mins (unclamped)
#define OFF_BCOL (2 * CHUNK_F)         // [16][8192] f : B col partial mins (unclamped)
#define OFF_CROW (3 * CHUNK_F)         // [16][8192] f : C row partial mins (unclamped)
#define OFF_BKEY (4 * CHUNK_F)         // [16][8192] u64 packed (clamped min, argmin)
#define OFF_BLK  (6 * CHUNK_F)         // [64][8] f per-block partial sums
#define OFF_CTR  (OFF_BLK + RB_BLOCKS * 8)  // 1 u32 completion counter
#define INF_BITS 0x7f800000u

// LDS pad: float4 index i stored at i + i/8 breaks the stride-8-float4
// (128 B) pattern that would put all 16 tx-lanes on the same bank quad.
#define PIDX(i) ((i) + ((i) >> 3))

typedef unsigned long long ull;

__device__ __forceinline__ float sqnorm3(float x, float y, float z) {
    // mimic jnp.sum(a*a, -1): squares then left-assoc add chain, no fma contraction
    return __fadd_rn(__fadd_rn(__fmul_rn(x, x), __fmul_rn(y, y)), __fmul_rn(z, z));
}

// point sources
#define SRC_T0  0
#define SRC_T1  1
#define SRC_T1H 2
#define SRC_Y0  3

// col=true: returns (-2x, -2y, -2z, sqnorm(x,y,z)); scaling by -2 is exact,
// so fadd(u, dot') == fsub(u, fmul(2, dot)) bit-exactly (validated earlier).
__device__ __forceinline__ float4 make_point(int src, bool col, int b, int i,
    const float* __restrict__ x, const float* __restrict__ m_hat,
    const float* __restrict__ y_hat0)
{
    float px, py, pz;
    if (src == SRC_Y0) {
        const float* p = y_hat0 + ((size_t)b * NPTS + i) * 3;
        px = p[0]; py = p[1]; pz = p[2];
    } else if (src == SRC_T1) {
        const float* p = x + ((size_t)(b * 2 + 1) * NPTS + i) * 3;
        px = p[0]; py = p[1]; pz = p[2];
    } else {
        const float* p = x + ((size_t)(b * 2 + 0) * NPTS + i) * 3;
        px = p[0]; py = p[1]; pz = p[2];
        if (src == SRC_T1H) {           // x_t0 + m_hat (same op order as before)
            const float* mh = m_hat + ((size_t)b * NPTS + i) * 3;
            px += mh[0]; py += mh[1]; pz += mh[2];
        }
    }
    float w = sqnorm3(px, py, pz);
    if (col) { px *= -2.0f; py *= -2.0f; pz *= -2.0f; }
    return make_float4(px, py, pz, w);
}

__device__ __forceinline__ ull shfl_xor_u64(ull v, int m) {
    int lo = __shfl_xor((int)(v & 0xFFFFFFFFull), m);
    int hi = __shfl_xor((int)(v >> 32), m);
    return ((ull)(unsigned)hi << 32) | (unsigned)lo;
}

// unclamped squared distance: mul, fma, fma, fadd, fadd (q pre-scaled by -2).
// Clamp max(.,0) is monotone -> hoisted outside min-reductions (bit-exact):
//   min_c max(d_c,0) == max(min_c d_c, 0)
__device__ __forceinline__ float dist_sq_raw(const float4& a, const float4& q) {
    float s = a.x * q.x + a.y * q.y + a.z * q.z;   // fma chain
    float u = __fadd_rn(a.w, q.w);
    return __fadd_rn(u, s);
}

// ---------------------------------------------------------------- pairwise
// grid: x = rowChunk(16)*colChunk(16) -> 256, y = batch(4), z = matrix(3)
// 3072 blocks = 12 blocks/CU. Each block: 128x128 tile, thread = 8x8 sub-tile,
// produces BOTH 128 row-partial-mins and 128 col-partial-mins per tile.
// No cross-lane ops in the inner 8x8 loop (pure ILP body); reductions at end.
__global__ __launch_bounds__(NT) void pairwise_kernel(
    const float* __restrict__ x, const float* __restrict__ m_hat,
    const float* __restrict__ y_hat0, float* __restrict__ ws)
{
    __shared__ float4 rowT[TM + TM / 8];   // padded: PIDX
    __shared__ float4 colT[TN + TN / 8];
    __shared__ float  colRed[4][TN];       // cross-wave col-min reduce

    int tid = threadIdx.x;
    int rowChunk = blockIdx.x >> 4;
    int colChunk = blockIdx.x & 15;
    int b   = blockIdx.y;
    int mat = blockIdx.z;

    // zero the rowreduce completion counter once per launch (any one thread;
    // pairwise fully completes before rowreduce starts, stream order)
    if (blockIdx.x == 0 && b == 0 && mat == 0 && tid == 0)
        ((unsigned*)ws)[OFF_CTR] = 0u;

    int rsrc, csrc;
    if (mat == 0)      { rsrc = SRC_T1H; csrc = SRC_T1; }
    else if (mat == 1) { rsrc = SRC_Y0;  csrc = SRC_T0; }
    else               { rsrc = SRC_Y0;  csrc = SRC_T1; }

    int rowBase = rowChunk * TM;
    int colBase = colChunk * TN;

    if (tid < TM) {
        rowT[PIDX(tid)] = make_point(rsrc, false, b, rowBase + tid, x, m_hat, y_hat0);
    } else {
        int t = tid - TM;
        colT[PIDX(t)] = make_point(csrc, true, b, colBase + t, x, m_hat, y_hat0);
    }
    __syncthreads();

    int tx = tid & 15, ty = tid >> 4;
    float4 a[8], q[8];
    #pragma unroll
    for (int i = 0; i < 8; ++i) a[i] = rowT[PIDX(ty * 8 + i)];   // broadcast groups
    #pragma unroll
    for (int j = 0; j < 8; ++j) q[j] = colT[PIDX(tx * 8 + j)];   // 2-way max (padded)

    if (mat == 1) {
        // B: row argmin (clamped, first-occurrence) + col min (unclamped)
        float rbest[8], cmin[8];
        int ridx[8];
        #pragma unroll
        for (int i = 0; i < 8; ++i) {
            rbest[i] = __uint_as_float(INF_BITS);
            cmin[i]  = __uint_as_float(INF_BITS);
            ridx[i]  = 0;
        }
        #pragma unroll
        for (int j = 0; j < 8; ++j) {
            #pragma unroll
            for (int i = 0; i < 8; ++i) {
                float d = dist_sq_raw(a[i], q[j]);
                cmin[j] = fminf(cmin[j], d);
                // argmin needs per-element clamped values (clamp can reorder
                // <=0 ties); ascending j + strict < keeps first occurrence
                float dc = fmaxf(d, 0.0f);
                if (dc < rbest[i]) { rbest[i] = dc; ridx[i] = j; }
            }
        }
        // pack (clamped bits << 32 | global col); u64-min => first-occurrence
        ull key[8];
        #pragma unroll
        for (int i = 0; i < 8; ++i)
            key[i] = ((ull)__float_as_uint(rbest[i]) << 32) |
                     (unsigned)(colBase + tx * 8 + ridx[i]);
        #pragma unroll
        for (int m = 1; m < 16; m <<= 1) {
            #pragma unroll
            for (int i = 0; i < 8; ++i) {
                ull o = shfl_xor_u64(key[i], m);
                key[i] = (o < key[i]) ? o : key[i];
            }
        }
        if (tx == 0) {
            ull* o = (ull*)(ws + OFF_BKEY) +
                     (size_t)colChunk * ROWS_TOT + b * NPTS + rowBase + ty * 8;
            #pragma unroll
            for (int i = 0; i < 8; ++i) o[i] = key[i];
        }
        // col-min: intra-wave across ty groups, then cross-wave via LDS
        #pragma unroll
        for (int j = 0; j < 8; ++j) {
            cmin[j] = fminf(cmin[j], __shfl_xor(cmin[j], 16));
            cmin[j] = fminf(cmin[j], __shfl_xor(cmin[j], 32));
        }
        int w = tid >> 6;
        if ((tid & 63) < 16) {
            #pragma unroll
            for (int j = 0; j < 8; ++j) colRed[w][tx * 8 + j] = cmin[j];
        }
        __syncthreads();
        if (tid < TN) {
            float v = fminf(fminf(colRed[0][tid], colRed[1][tid]),
                            fminf(colRed[2][tid], colRed[3][tid]));
            ws[OFF_BCOL + (size_t)rowChunk * ROWS_TOT + b * NPTS + colBase + tid] = v;
        }
    } else if (mat == 0) {
        // A: row min (dist1 partial) + col min (dist2 partial), both unclamped
        float rmin[8], cmin[8];
        #pragma unroll
        for (int i = 0; i < 8; ++i) {
            rmin[i] = __uint_as_float(INF_BITS);
            cmin[i] = __uint_as_float(INF_BITS);
        }
        #pragma unroll
        for (int j = 0; j < 8; ++j) {
            #pragma unroll
            for (int i = 0; i < 8; ++i) {
                float d = dist_sq_raw(a[i], q[j]);
                rmin[i] = fminf(rmin[i], d);
                cmin[j] = fminf(cmin[j], d);
            }
        }
        #pragma unroll
        for (int m = 1; m < 16; m <<= 1) {
            #pragma unroll
            for (int i = 0; i < 8; ++i)
                rmin[i] = fminf(rmin[i], __shfl_xor(rmin[i], m));
        }
        if (tx == 0) {
            float* o = ws + OFF_AROW +
                       (size_t)colChunk * ROWS_TOT + b * NPTS + rowBase + ty * 8;
            *(float4*)(o)     = make_float4(rmin[0], rmin[1], rmin[2], rmin[3]);
            *(float4*)(o + 4) = make_float4(rmin[4], rmin[5], rmin[6], rmin[7]);
        }
        #pragma unroll
        for (int j = 0; j < 8; ++j) {
            cmin[j] = fminf(cmin[j], __shfl_xor(cmin[j], 16));
            cmin[j] = fminf(cmin[j], __shfl_xor(cmin[j], 32));
        }
        int w = tid >> 6;
        if ((tid & 63) < 16) {
            #pragma unroll
            for (int j = 0; j < 8; ++j) colRed[w][tx * 8 + j] = cmin[j];
        }
        __syncthreads();
        if (tid < TN) {
            float v = fminf(fminf(colRed[0][tid], colRed[1][tid]),
                            fminf(colRed[2][tid], colRed[3][tid]));
            ws[OFF_ACOL + (size_t)rowChunk * ROWS_TOT + b * NPTS + colBase + tid] = v;
        }
    } else {
        // C: row min only (unclamped)
        float rmin[8];
        #pragma unroll
        for (int i = 0; i < 8; ++i) rmin[i] = __uint_as_float(INF_BITS);
        #pragma unroll
        for (int j = 0; j < 8; ++j) {
            #pragma unroll
            for (int i = 0; i < 8; ++i)
                rmin[i] = fminf(rmin[i], dist_sq_raw(a[i], q[j]));
        }
        #pragma unroll
        for (int m = 1; m < 16; m <<= 1) {
            #pragma unroll
            for (int i = 0; i < 8; ++i)
                rmin[i] = fminf(rmin[i], __shfl_xor(rmin[i], m));
        }
        if (tx == 0) {
            float* o = ws + OFF_CROW +
                       (size_t)colChunk * ROWS_TOT + b * NPTS + rowBase + ty * 8;
            *(float4*)(o)     = make_float4(rmin[0], rmin[1], rmin[2], rmin[3]);
            *(float4*)(o + 4) = make_float4(rmin[4], rmin[5], rmin[6], rmin[7]);
        }
    }
}

// ---------------------------------------------------------------- row reduce + finalize
// grid: 64 blocks x 256. 2 threads per row (8 chunks each), shfl_xor combine,
// hoisted clamp applied once per row, per-block partial sums -> OFF_BLK.
// Last-done block (atomic counter) performs the final combine with the SAME
// summation tree as the old final_kernel (bit-exact). Cross-XCD visibility of
// OFF_BLK partials via agent-scope atomic store/load + threadfence.
__global__ __launch_bounds__(NT) void rowreduce_kernel(
    const float* __restrict__ m_hat, const float* __restrict__ y_hat0,
    const float* __restrict__ y_hat1, float* __restrict__ ws,
    float* __restrict__ out)
{
    int tid  = threadIdx.x;
    int row  = blockIdx.x * 128 + (tid >> 1);   // [0, 8192)
    int half = tid & 1;
    int b    = row >> 11;

    const ull* bkey = (const ull*)(ws + OFF_BKEY);

    float d1m = __uint_as_float(INF_BITS), d2m = d1m, c1m = d1m, r3m = d1m;
    ull k2 = ~0ull;
    #pragma unroll
    for (int c = 0; c < 8; ++c) {
        int idx = (half * 8 + c) * ROWS_TOT + row;
        d1m = fminf(d1m, ws[OFF_AROW + idx]);
        d2m = fminf(d2m, ws[OFF_ACOL + idx]);
        c1m = fminf(c1m, ws[OFF_BCOL + idx]);
        r3m = fminf(r3m, ws[OFF_CROW + idx]);
        ull kk = bkey[idx];
        k2 = (kk < k2) ? kk : k2;
    }
    d1m = fminf(d1m, __shfl_xor(d1m, 1));
    d2m = fminf(d2m, __shfl_xor(d2m, 1));
    c1m = fminf(c1m, __shfl_xor(c1m, 1));
    r3m = fminf(r3m, __shfl_xor(r3m, 1));
    { ull o = shfl_xor_u64(k2, 1); k2 = (o < k2) ? o : k2; }

    // hoisted clamps (bit-exact: max monotone commutes with min)
    d1m = fmaxf(d1m, 0.0f);
    d2m = fmaxf(d2m, 0.0f);
    c1m = fmaxf(c1m, 0.0f);
    r3m = fmaxf(r3m, 0.0f);

    float d2sq = __uint_as_float((unsigned)(k2 >> 32));
    unsigned idxm = (unsigned)(k2 & 0xFFFFFFFFull);
    float md   = (sqrtf(d2sq) < 0.05f) ? 1.0f : 0.0f;
    float dcat = fminf(d2sq, r3m);
    float mneg = (sqrtf(dcat) > 0.2f) ? 1.0f : 0.0f;

    const float* p0 = y_hat0 + (size_t)row * 3;
    const float* p1 = y_hat1 + (size_t)row * 3;
    const float* nm = m_hat + ((size_t)b * NPTS + idxm) * 3;

    float dyn = 0.f, stat = 0.f;
    #pragma unroll
    for (int k = 0; k < 3; ++k) {
        float diff = p1[k] - p0[k];
        float e = md * (diff - nm[k]);      // masks are 0/1 -> exact
        dyn += e * e;
        float s = mneg * diff;
        stat += s * s;
    }
    float cs = (c1m < 0.1f) ? c1m : 0.f;
    float cn = (c1m < 0.1f) ? 1.f  : 0.f;
    float s1 = d1m, s2 = d2m;
    if (half) { s1 = s2 = cs = cn = dyn = stat = 0.f; }   // avoid double count

    #pragma unroll
    for (int off = 32; off > 0; off >>= 1) {
        s1  += __shfl_down(s1,  off);
        s2  += __shfl_down(s2,  off);
        cs  += __shfl_down(cs,  off);
        cn  += __shfl_down(cn,  off);
        dyn += __shfl_down(dyn, off);
        stat+= __shfl_down(stat,off);
    }
    __shared__ float sm[4][6];
    __shared__ int lastBlock;
    int wv = tid >> 6, ln = tid & 63;
    if (ln == 0) {
        sm[wv][0] = s1; sm[wv][1] = s2; sm[wv][2] = cs;
        sm[wv][3] = cn; sm[wv][4] = dyn; sm[wv][5] = stat;
    }
    __syncthreads();
    if (tid == 0) {
        #pragma unroll
        for (int j = 0; j < 6; ++j) {
            float v = sm[0][j] + sm[1][j] + sm[2][j] + sm[3][j];
            __hip_atomic_store(ws + OFF_BLK + blockIdx.x * 8 + j, v,
                               __ATOMIC_RELAXED, __HIP_MEMORY_SCOPE_AGENT);
        }
        __threadfence();   // release partials before signaling
        unsigned old = atomicAdd(((unsigned*)ws) + OFF_CTR, 1u);
        lastBlock = (old == RB_BLOCKS - 1) ? 1 : 0;
    }
    __syncthreads();

    // -------- final combine (only the last-finished block, wave 0) --------
    if (lastBlock != 0 && tid < 64) {
        __threadfence();   // acquire side
        int lane = tid;
        float v[6];
        #pragma unroll
        for (int j = 0; j < 6; ++j)
            v[j] = __hip_atomic_load(ws + OFF_BLK + lane * 8 + j,
                                     __ATOMIC_RELAXED, __HIP_MEMORY_SCOPE_AGENT);
        // identical 16-lane tree as the old final_kernel (bit-exact)
        #pragma unroll
        for (int off = 8; off > 0; off >>= 1) {
            #pragma unroll
            for (int j = 0; j < 6; ++j) {
                float t = __shfl_down(v[j], off);
                if (((lane & 15) + off) < 16) v[j] += t;
            }
        }
        // per-batch group sums live in lanes 0,16,32,48 -> gather via shfl
        float g1[6], g2[6], g3[6];
        #pragma unroll
        for (int j = 0; j < 6; ++j) {
            g1[j] = __shfl(v[j], 16);
            g2[j] = __shfl(v[j], 32);
            g3[j] = __shfl(v[j], 48);
        }
        if (lane == 0) {
            float bsm[4][6];
            #pragma unroll
            for (int j = 0; j < 6; ++j) {
                bsm[0][j] = v[j];  bsm[1][j] = g1[j];
                bsm[2][j] = g2[j]; bsm[3][j] = g3[j];
            }
            float dyn2 = 0.f, stat2 = 0.f, cs2 = 0.f, cn2 = 0.f;
            #pragma unroll
            for (int bb = 0; bb < 4; ++bb) {
                float lc = bsm[bb][0] / (float)NPTS + bsm[bb][1] / (float)NPTS;
                float maskc = (lc < 0.1f) ? 1.0f : 0.0f;
                dyn2  += maskc * bsm[bb][4];
                stat2 += bsm[bb][5];
                cs2   += bsm[bb][2];
                cn2   += bsm[bb][3];
            }
            const float denom = (float)(BATCH * NPTS * 3);   // 24576
            out[0] = dyn2 / denom;
            out[1] = stat2 / denom;
            out[2] = cs2 / fmaxf(cn2, 1.0f);
        }
    }
}

extern "C" void kernel_launch(void* const* d_in, const int* in_sizes, int n_in,
                              void* d_out, int out_size, void* d_ws, size_t ws_size,
                              hipStream_t stream)
{
    const float* x      = (const float*)d_in[0];
    const float* m_hat  = (const float*)d_in[1];
    const float* y_hat0 = (const float*)d_in[2];
    const float* y_hat1 = (const float*)d_in[3];
    float* ws  = (float*)d_ws;
    float* out = (float*)d_out;

    pairwise_kernel<<<dim3(CH * CH, BATCH, 3), dim3(NT), 0, stream>>>(
        x, m_hat, y_hat0, ws);
    rowreduce_kernel<<<dim3(RB_BLOCKS), dim3(NT), 0, stream>>>(
        m_hat, y_hat0, y_hat1, ws, out);
}